// Round 17
// baseline (85.633 us; speedup 1.0000x reference)
//
#include <hip/hip_runtime.h>
#include <cstdint>
#include <cstddef>

#define T_N    32768
#define N_SEG  2048
#define DSEQ   128
#define DLSTM  512
#define DX     512
#define DPROJ  1024
#define OUTW   2048
#define WSCALE 2873.6827f                 // 127*sqrt(512)
#define SXQ    15.875f                    // 127/8: DEQX = 8*DEQH (integer fold)
#define LOG2E2 2.8853900817779268f        // 2*log2(e)
#define DEQH   (2.8853900817779268f/(2873.6827f*127.0f))
#define MAGICF 12582912.0f                // 1.5*2^23 RNE round-to-int trick
#define MAGIC_C (12582912.0f + 127.0f)

typedef __attribute__((ext_vector_type(8))) short short8;
typedef __attribute__((ext_vector_type(4))) float f32x4;
typedef __attribute__((ext_vector_type(4))) int i32x4;

#if __has_builtin(__builtin_amdgcn_exp2f)
#define EXP2F(x) __builtin_amdgcn_exp2f(x)
#else
#define EXP2F(x) __expf((x) * 0.6931471805599453f)
#endif
#if __has_builtin(__builtin_amdgcn_rcpf)
#define RCPF(x) __builtin_amdgcn_rcpf(x)
#else
#define RCPF(x) (1.0f / (x))
#endif

// opaque pin: keeps loaded values register-resident (blocks load-sinking/remat)
#define PIN(x) asm volatile("" : "+v"(x))

__device__ inline unsigned int cvtpk(float a, float b) {
  unsigned int r;
  asm("v_cvt_pk_bf16_f32 %0, %1, %2" : "=v"(r) : "v"(a), "v"(b));
  return r;
}

// pack low bytes of 4 words -> one word (3 x v_perm_b32)
__device__ inline unsigned pack4(unsigned b0, unsigned b1, unsigned b2, unsigned b3) {
#if __has_builtin(__builtin_amdgcn_perm)
  unsigned lo = __builtin_amdgcn_perm(b1, b0, 0x00000400u);
  unsigned hi = __builtin_amdgcn_perm(b3, b2, 0x00000400u);
  return __builtin_amdgcn_perm(hi, lo, 0x05040100u);
#else
  return (b0 & 255u) | ((b1 & 255u) << 8) | ((b2 & 255u) << 16) | (b3 << 24);
#endif
}

// ================= launch 1: prep (fully parallel, 256-thr blocks) =================
// bid [0,128): seg bounds. bid [128,256): W_hh i8 frag pack. bid [256,288): W_ih pack.
// 8-wave layout: W8 id = (((dir*8+wv)*4+mt)*8+kt)*64+lane ;
//                WX8 id = (((dir*8+wv)*4+mt)*2+kt)*64+lane
// row perm: rr=lane&15 -> n = wv*64 + (rr>>2)*16 + mt*4 + (rr&3) ; k = kt*64+(lane>>4)*16+j
__global__ __launch_bounds__(256) void prep_kernel(
    const int* __restrict__ masks,
    const float* __restrict__ Whh_f, const float* __restrict__ Whh_b,
    const float* __restrict__ Wih_f, const float* __restrict__ Wih_b,
    signed char* __restrict__ W8, signed char* __restrict__ WX8,
    int* __restrict__ seg_start, int* __restrict__ seg_end,
    int* __restrict__ tile_ctr) {
  const int bid = blockIdx.x, tid = threadIdx.x;
  if (bid == 0 && tid == 0) *tile_ctr = 0;
  if (bid < 128) {
    int t = bid * 256 + tid;
    int m = masks[t];
    if (t == 0 || masks[t - 1] != m) seg_start[m] = t;
    if (t == T_N - 1 || masks[t + 1] != m) seg_end[m] = t + 1;
  } else if (bid < 256) {
    int id = (bid - 128) * 256 + tid;   // < 32768
    int lane = id & 63;
    int kt = (id >> 6) & 7;
    int mt = (id >> 9) & 3;
    int wv = (id >> 11) & 7;
    int dir = id >> 14;
    int rr = lane & 15;
    int n = wv * 64 + (rr >> 2) * 16 + mt * 4 + (rr & 3);
    int k0 = kt * 64 + (lane >> 4) * 16;
    const float* wp = (dir ? Whh_b : Whh_f) + (size_t)n * DLSTM + k0;
    signed char pkt[16];
#pragma unroll
    for (int q = 0; q < 4; ++q) {
      float4 v = *(const float4*)(wp + q * 4);
      float vv[4] = {v.x, v.y, v.z, v.w};
#pragma unroll
      for (int j = 0; j < 4; ++j) {
        int qq = (int)rintf(vv[j] * WSCALE);
        qq = qq > 127 ? 127 : (qq < -127 ? -127 : qq);
        pkt[q * 4 + j] = (signed char)qq;
      }
    }
    i32x4 v16;
    __builtin_memcpy(&v16, pkt, 16);
    *(i32x4*)&W8[(size_t)id * 16] = v16;
  } else {
    int id = (bid - 256) * 256 + tid;  // < 8192
    int lane = id & 63;
    int kt = (id >> 6) & 1;
    int mt = (id >> 7) & 3;
    int wv = (id >> 9) & 7;
    int dir = id >> 12;
    int rr = lane & 15;
    int n = wv * 64 + (rr >> 2) * 16 + mt * 4 + (rr & 3);
    int k0 = kt * 64 + (lane >> 4) * 16;
    const float* wp = (dir ? Wih_b : Wih_f) + (size_t)n * DSEQ + k0;
    signed char pkt[16];
#pragma unroll
    for (int q = 0; q < 4; ++q) {
      float4 v = *(const float4*)(wp + q * 4);
      float vv[4] = {v.x, v.y, v.z, v.w};
#pragma unroll
      for (int j = 0; j < 4; ++j) {
        int qq = (int)rintf(vv[j] * WSCALE);
        qq = qq > 127 ? 127 : (qq < -127 ? -127 : qq);
        pkt[q * 4 + j] = (signed char)qq;
      }
    }
    i32x4 v16;
    __builtin_memcpy(&v16, pkt, 16);
    *(i32x4*)&WX8[(size_t)id * 16] = v16;
  }
}

// ================= launch 2: counting sort (desc) from precomputed bounds =================
__global__ __launch_bounds__(1024) void csort_kernel(
    const int* __restrict__ seg_start, const int* __restrict__ seg_end,
    int* __restrict__ s_sid, int* __restrict__ s_st, int* __restrict__ s_ln) {
  __shared__ int A_[2048];
  __shared__ int B_[2048];
  const int tid = threadIdx.x;
  for (int i = tid; i < 2048; i += 1024) A_[i] = 0;
  __syncthreads();
  for (int i = tid; i < N_SEG; i += 1024) {
    int len = seg_end[i] - seg_start[i];
    atomicAdd(&A_[len < 2047 ? len : 2047], 1);
  }
  __syncthreads();
  int* src = A_;
  int* dst = B_;
  for (int d = 1; d < 2048; d <<= 1) {
    for (int i = tid; i < 2048; i += 1024) {
      int v = src[i];
      if (i + d < 2048) v += src[i + d];
      dst[i] = v;
    }
    __syncthreads();
    int* tp = src; src = dst; dst = tp;
  }
  for (int i = tid; i < 2048; i += 1024)
    dst[i] = (i + 1 < 2048) ? src[i + 1] : 0;
  __syncthreads();
  for (int i = tid; i < N_SEG; i += 1024) {
    int st = seg_start[i];
    int len = seg_end[i] - st;
    int b = len < 2047 ? len : 2047;
    int pos = atomicAdd(&dst[b], 1);
    s_sid[pos] = i;
    s_st[pos] = st;
    s_ln[pos] = len;
  }
}

// ================= launch 3: fused scan (+input proj) + queued proj GEMM =================
// grid 256, block 512 (8 waves). Antipodal: bid=2i+dir -> batch (dir ? 127-i : i).
__global__ __launch_bounds__(512, 2) void fused_kernel(
    const float* __restrict__ seqs,
    const signed char* __restrict__ W8, const signed char* __restrict__ WX8,
    const int* __restrict__ s_sid_g, const int* __restrict__ s_st_g,
    const int* __restrict__ s_ln_g,
    const float* __restrict__ b_f, const float* __restrict__ b_b,
    const float* __restrict__ x, const float* __restrict__ Wx,
    const float* __restrict__ bx, float* __restrict__ out,
    int* __restrict__ tile_ctr) {
  __shared__ __align__(16) char smem[21760];
  const int bid = blockIdx.x, tid = threadIdx.x;
  const int wv = tid >> 6, lane = tid & 63;

  // ---------------- scan phase ----------------
  {
    const int dir = bid & 1;
    const int idx = bid >> 1;
    const int bb = dir ? (127 - idx) : idx;
    const int chain = lane & 15, kgrp = lane >> 4;
    const int dbase = wv << 6;
    signed char* H = (signed char*)smem;             // [2][16][528]
    signed char* Xs = (signed char*)(smem + 16896);  // [2][16][144]
    int* meta = (int*)(smem + 21504);                // sid[16] | st[16] | ln[16]

    if (tid < 16) {
      meta[tid] = s_sid_g[bb * 16 + tid];
      meta[16 + tid] = s_st_g[bb * 16 + tid];
      meta[32 + tid] = s_ln_g[bb * 16 + tid];
    }
    {  // zero H[0]: 16 rows x 512B, 16B/thread
      int r = tid >> 5, o = (tid & 31) << 4;
      *(i32x4*)(H + r * 528 + o) = (i32x4){0, 0, 0, 0};
    }

    // register-resident weights: W_hh 32 frags (128 regs) + W_ih 8 frags (32 regs)
    i32x4 w[4][8], wx[4][2];
    {
      const signed char* wb = W8 + ((size_t)((dir << 3) + wv) << 15) + (lane << 4);
#pragma unroll
      for (int mt = 0; mt < 4; ++mt)
#pragma unroll
        for (int kt = 0; kt < 8; ++kt)
          w[mt][kt] = *(const i32x4*)(wb + (mt * 8 + kt) * 1024);
      const signed char* wxb = WX8 + ((size_t)((dir << 3) + wv) << 13) + (lane << 4);
#pragma unroll
      for (int mt = 0; mt < 4; ++mt)
#pragma unroll
        for (int kt = 0; kt < 2; ++kt)
          wx[mt][kt] = *(const i32x4*)(wxb + (mt * 2 + kt) * 1024);
    }
#pragma unroll
    for (int mt = 0; mt < 4; ++mt) {
#pragma unroll
      for (int kt = 0; kt < 8; ++kt) PIN(w[mt][kt]);
      PIN(wx[mt][0]); PIN(wx[mt][1]);
    }

    float bsc[16];
    {
      const float* bp = (dir ? b_b : b_f) + dbase + (kgrp << 4);
#pragma unroll
      for (int mt = 0; mt < 4; ++mt) {
        float4 u = *(const float4*)(bp + mt * 4);
        bsc[mt * 4 + 0] = u.x * LOG2E2; bsc[mt * 4 + 1] = u.y * LOG2E2;
        bsc[mt * 4 + 2] = u.z * LOG2E2; bsc[mt * 4 + 3] = u.w * LOG2E2;
      }
    }
    __syncthreads();

    const int maxlen = meta[32];   // sorted desc -> first is batch max
    const int myLen = meta[32 + chain];
    const int csn = (wv << 1) + (lane >> 5);           // chain this thread stages
    const int stStart = meta[16 + csn], stLen = meta[32 + csn];
    const int jx = (lane & 31) << 2;                   // 4 floats of seq row

    // prologue: stage x(0) into Xs[0], preload x(1) into regs
    {
      int t0 = dir ? (stStart + stLen - 1) : stStart;
      float4 xv0 = *(const float4*)(seqs + (size_t)t0 * DSEQ + jx);
      unsigned c0 = __float_as_uint(fminf(fmaxf(xv0.x * SXQ, -127.f), 127.f) + MAGICF);
      unsigned c1 = __float_as_uint(fminf(fmaxf(xv0.y * SXQ, -127.f), 127.f) + MAGICF);
      unsigned c2 = __float_as_uint(fminf(fmaxf(xv0.z * SXQ, -127.f), 127.f) + MAGICF);
      unsigned c3 = __float_as_uint(fminf(fmaxf(xv0.w * SXQ, -127.f), 127.f) + MAGICF);
      *(unsigned*)(Xs + csn * 144 + jx) = pack4(c0, c1, c2, c3);
    }
    float4 xvB;   // x(s+1), written to Xs during step s
    {
      int sn = (1 < stLen) ? 1 : (stLen - 1);
      int t = dir ? (stStart + stLen - 1 - sn) : (stStart + sn);
      xvB = *(const float4*)(seqs + (size_t)t * DSEQ + jx);
    }
    __syncthreads();

    float pool[4][4];
#pragma unroll
    for (int mt = 0; mt < 4; ++mt)
#pragma unroll
      for (int r = 0; r < 4; ++r) pool[mt][r] = 0.f;

    int cur = 0;
    for (int s = 0; s < maxlen; ++s) {
      // issue x(s+2) load (consumed next iteration; full step of cover)
      float4 xvC;
      {
        int sn = (s + 2 < stLen) ? (s + 2) : (stLen - 1);
        int t = dir ? (stStart + stLen - 1 - sn) : (stStart + sn);
        xvC = *(const float4*)(seqs + (size_t)t * DSEQ + jx);
      }

      i32x4 acc[4], ax[4];
#pragma unroll
      for (int mt = 0; mt < 4; ++mt) {
        acc[mt] = (i32x4){0, 0, 0, 0};
        ax[mt] = (i32x4){0, 0, 0, 0};
      }
      const float msk = (s < myLen) ? 1.f : 0.f;
      signed char* hwbase = H + (cur ^ 1) * 8448 + chain * 528 + dbase + (kgrp << 4);

      __builtin_amdgcn_s_setprio(1);
      // x-projection MFMAs (read Xs[cur])
      {
        const signed char* xr = Xs + cur * 2304 + chain * 144;
#pragma unroll
        for (int kt = 0; kt < 2; ++kt) {
          i32x4 xb = *(const i32x4*)(xr + kt * 64 + (kgrp << 4));
#pragma unroll
          for (int mt = 0; mt < 4; ++mt)
            ax[mt] = __builtin_amdgcn_mfma_i32_16x16x64_i8(wx[mt][kt], xb, ax[mt], 0, 0, 0);
        }
      }
      // write x(s+1) to Xs[cur^1] now (Xs[cur] reads issued above; early drain)
      {
        unsigned c0 = __float_as_uint(fminf(fmaxf(xvB.x * SXQ, -127.f), 127.f) + MAGICF);
        unsigned c1 = __float_as_uint(fminf(fmaxf(xvB.y * SXQ, -127.f), 127.f) + MAGICF);
        unsigned c2 = __float_as_uint(fminf(fmaxf(xvB.z * SXQ, -127.f), 127.f) + MAGICF);
        unsigned c3 = __float_as_uint(fminf(fmaxf(xvB.w * SXQ, -127.f), 127.f) + MAGICF);
        *(unsigned*)(Xs + (cur ^ 1) * 2304 + csn * 144 + jx) = pack4(c0, c1, c2, c3);
      }

      const signed char* hr = H + cur * 8448 + chain * 528;
      // interleave: chain(0), chain(1), epi(0), chain(2), epi(1), chain(3), epi(2), epi(3)
#define HCHAIN(mt)                                                                      \
  {                                                                                     \
    _Pragma("unroll")                                                                   \
    for (int kt = 0; kt < 8; ++kt) {                                                    \
      i32x4 hb = *(const i32x4*)(hr + kt * 64 + (kgrp << 4));                           \
      acc[mt] = __builtin_amdgcn_mfma_i32_16x16x64_i8(w[mt][kt], hb, acc[mt], 0, 0, 0); \
    }                                                                                   \
  }
#define EPI(mt)                                                                     \
  {                                                                                 \
    unsigned b0, b1, b2, b3;                                                        \
    {                                                                               \
      int comb = acc[mt][0] + (ax[mt][0] << 3);                                     \
      float rc = RCPF(EXP2F(fmaf((float)comb, DEQH, bsc[mt * 4 + 0])) + 1.f);       \
      pool[mt][0] = fmaf(rc, msk, pool[mt][0]);                                     \
      b0 = __float_as_uint(fmaf(-254.f, rc, MAGIC_C));                              \
    }                                                                               \
    {                                                                               \
      int comb = acc[mt][1] + (ax[mt][1] << 3);                                     \
      float rc = RCPF(EXP2F(fmaf((float)comb, DEQH, bsc[mt * 4 + 1])) + 1.f);       \
      pool[mt][1] = fmaf(rc, msk, pool[mt][1]);                                     \
      b1 = __float_as_uint(fmaf(-254.f, rc, MAGIC_C));                              \
    }                                                                               \
    {                                                                               \
      int comb = acc[mt][2] + (ax[mt][2] << 3);                                     \
      float rc = RCPF(EXP2F(fmaf((float)comb, DEQH, bsc[mt * 4 + 2])) + 1.f);       \
      pool[mt][2] = fmaf(rc, msk, pool[mt][2]);                                     \
      b2 = __float_as_uint(fmaf(-254.f, rc, MAGIC_C));                              \
    }                                                                               \
    {                                                                               \
      int comb = acc[mt][3] + (ax[mt][3] << 3);                                     \
      float rc = RCPF(EXP2F(fmaf((float)comb, DEQH, bsc[mt * 4 + 3])) + 1.f);       \
      pool[mt][3] = fmaf(rc, msk, pool[mt][3]);                                     \
      b3 = __float_as_uint(fmaf(-254.f, rc, MAGIC_C));                              \
    }                                                                               \
    *(unsigned*)(hwbase + mt * 4) = pack4(b0, b1, b2, b3);                          \
  }
      HCHAIN(0)
      HCHAIN(1)
      EPI(0)
      HCHAIN(2)
      EPI(1)
      HCHAIN(3)
      EPI(2)
      EPI(3)
#undef HCHAIN
#undef EPI
      __builtin_amdgcn_s_setprio(0);

      asm volatile("s_waitcnt lgkmcnt(0)" ::: "memory");
      __builtin_amdgcn_s_barrier();
      __builtin_amdgcn_sched_barrier(0);
      xvB = xvC;
      cur ^= 1;
    }

    const int sid = meta[chain];
    const float s2 = -2.0f / (float)myLen;
    float* op = out + (size_t)sid * OUTW + DPROJ + dir * DLSTM + dbase + (kgrp << 4);
#pragma unroll
    for (int mt = 0; mt < 4; ++mt)
      *(float4*)(op + mt * 4) =
          make_float4(fmaf(s2, pool[mt][0], 1.f), fmaf(s2, pool[mt][1], 1.f),
                      fmaf(s2, pool[mt][2], 1.f), fmaf(s2, pool[mt][3], 1.f));
  }

  // ---------------- queued proj GEMM: blocks pull 128x128 tiles as they free up ----------------
  {
    int* tileslot = (int*)(smem + 21696);
    unsigned short (*As)[40] = (unsigned short(*)[40])smem;               // [128][40]
    unsigned short (*Bs)[40] = (unsigned short(*)[40])(smem + 10240);     // [128][40]
    const int rowA = lane & 15, kgrp = lane >> 4;
    const int wm = (wv & 1) << 6, wn = (wv >> 1) << 5;
    const int srow = tid >> 2, skc = (tid & 3) << 3;

    for (;;) {
      __syncthreads();   // smem quiescent (scan done / previous tile done)
      if (tid == 0) *tileslot = atomicAdd(tile_ctr, 1);
      __syncthreads();
      const int tile = *tileslot;
      if (tile >= 128) break;
      const int m0 = (tile >> 3) << 7, n0 = (tile & 7) << 7;

      f32x4 acc[4][2];
#pragma unroll
      for (int i = 0; i < 4; ++i)
#pragma unroll
        for (int j = 0; j < 2; ++j) acc[i][j] = (f32x4){0.f, 0.f, 0.f, 0.f};

      for (int k0 = 0; k0 < DX; k0 += 32) {
        __syncthreads();
        {
          const float* ap = x + (size_t)(m0 + srow) * DX + k0 + skc;
          float4 va0 = *(const float4*)ap;
          float4 va1 = *(const float4*)(ap + 4);
          unsigned wa[4] = {cvtpk(va0.x, va0.y), cvtpk(va0.z, va0.w),
                            cvtpk(va1.x, va1.y), cvtpk(va1.z, va1.w)};
          *(uint4*)&As[srow][skc] = *(uint4*)wa;
          const float* bp = Wx + (size_t)(n0 + srow) * DX + k0 + skc;
          float4 vb0 = *(const float4*)bp;
          float4 vb1 = *(const float4*)(bp + 4);
          unsigned wb2[4] = {cvtpk(vb0.x, vb0.y), cvtpk(vb0.z, vb0.w),
                             cvtpk(vb1.x, vb1.y), cvtpk(vb1.z, vb1.w)};
          *(uint4*)&Bs[srow][skc] = *(uint4*)wb2;
        }
        __syncthreads();
        short8 af[4], bf[2];
#pragma unroll
        for (int mt = 0; mt < 4; ++mt)
          af[mt] = *(const short8*)&As[wm + mt * 16 + rowA][kgrp << 3];
#pragma unroll
        for (int nt = 0; nt < 2; ++nt)
          bf[nt] = *(const short8*)&Bs[wn + nt * 16 + rowA][kgrp << 3];
#pragma unroll
        for (int mt = 0; mt < 4; ++mt)
#pragma unroll
          for (int nt = 0; nt < 2; ++nt)
            acc[mt][nt] = __builtin_amdgcn_mfma_f32_16x16x32_bf16(af[mt], bf[nt], acc[mt][nt], 0, 0, 0);
      }

#pragma unroll
      for (int mt = 0; mt < 4; ++mt)
#pragma unroll
        for (int nt = 0; nt < 2; ++nt) {
          int n = n0 + wn + nt * 16 + rowA;
          float bv = bx[n];
#pragma unroll
          for (int r = 0; r < 4; ++r) {
            int m = m0 + wm + mt * 16 + (kgrp << 2) + r;
            out[(size_t)m * OUTW + n] = acc[mt][nt][r] + bv;
          }
        }
    }
  }
}

extern "C" void kernel_launch(void* const* d_in, const int* in_sizes, int n_in,
                              void* d_out, int out_size, void* d_ws, size_t ws_size,
                              hipStream_t stream) {
  const float* x     = (const float*)d_in[0];
  const float* seqs  = (const float*)d_in[1];
  const int*   masks = (const int*)d_in[2];
  const float* Wih_f = (const float*)d_in[3];
  const float* Whh_f = (const float*)d_in[4];
  const float* b_f   = (const float*)d_in[5];
  const float* Wih_b = (const float*)d_in[6];
  const float* Whh_b = (const float*)d_in[7];
  const float* b_b   = (const float*)d_in[8];
  const float* Wx    = (const float*)d_in[9];
  const float* bx    = (const float*)d_in[10];
  float* out = (float*)d_out;

  char* ws = (char*)d_ws;
  signed char* W8  = (signed char*)ws;                        // 512 KB
  signed char* WX8 = (signed char*)(ws + (size_t)512 * 1024); // 128 KB
  int* seg_start = (int*)(ws + (size_t)640 * 1024);
  int* seg_end   = seg_start + N_SEG;
  int* s_sid     = seg_end + N_SEG;
  int* s_st      = s_sid + N_SEG;
  int* s_ln      = s_st + N_SEG;
  int* tile_ctr  = s_ln + N_SEG;

  prep_kernel<<<288, 256, 0, stream>>>(masks, Whh_f, Whh_b, Wih_f, Wih_b,
                                       W8, WX8, seg_start, seg_end, tile_ctr);
  csort_kernel<<<1, 1024, 0, stream>>>(seg_start, seg_end, s_sid, s_st, s_ln);
  fused_kernel<<<256, 512, 0, stream>>>(seqs, W8, WX8, s_sid, s_st, s_ln,
                                        b_f, b_b, x, Wx, bx, out, tile_ctr);
}

// Round 18
// 64.157 us; speedup vs baseline: 1.3347x; 1.3347x over previous
//
#include <hip/hip_runtime.h>
#include <cstdint>
#include <cstddef>

#define T_N    32768
#define N_SEG  2048
#define DSEQ   128
#define DLSTM  512
#define DX     512
#define DPROJ  1024
#define OUTW   2048
#define WSCALE 2873.6827f                 // 127*sqrt(512)
#define SXQ    15.875f                    // 127/8: DEQX = 8*DEQH (integer fold)
#define LOG2E2 2.8853900817779268f        // 2*log2(e)
#define DEQH   (2.8853900817779268f/(2873.6827f*127.0f))
#define MAGICF 12582912.0f                // 1.5*2^23 RNE round-to-int trick
#define MAGIC_C (12582912.0f + 127.0f)

typedef __attribute__((ext_vector_type(8))) short short8;
typedef __attribute__((ext_vector_type(4))) float f32x4;
typedef __attribute__((ext_vector_type(4))) int i32x4;

#if __has_builtin(__builtin_amdgcn_exp2f)
#define EXP2F(x) __builtin_amdgcn_exp2f(x)
#else
#define EXP2F(x) __expf((x) * 0.6931471805599453f)
#endif
#if __has_builtin(__builtin_amdgcn_rcpf)
#define RCPF(x) __builtin_amdgcn_rcpf(x)
#else
#define RCPF(x) (1.0f / (x))
#endif

// opaque pin: keeps loaded values register-resident (blocks load-sinking/remat)
#define PIN(x) asm volatile("" : "+v"(x))

__device__ inline unsigned int cvtpk(float a, float b) {
  unsigned int r;
  asm("v_cvt_pk_bf16_f32 %0, %1, %2" : "=v"(r) : "v"(a), "v"(b));
  return r;
}

// ================= launch 1: prep (weight packs only, fully parallel) =================
// bid [0,128): W_hh i8 frag pack. bid [128,160): W_ih pack.
// 8-wave layout: W8 id = (((dir*8+wv)*4+mt)*8+kt)*64+lane ;
//                WX8 id = (((dir*8+wv)*4+mt)*2+kt)*64+lane
// row perm: rr=lane&15 -> n = wv*64 + (rr>>2)*16 + mt*4 + (rr&3) ; k = kt*64+(lane>>4)*16+j
__global__ __launch_bounds__(256) void prep_kernel(
    const float* __restrict__ Whh_f, const float* __restrict__ Whh_b,
    const float* __restrict__ Wih_f, const float* __restrict__ Wih_b,
    signed char* __restrict__ W8, signed char* __restrict__ WX8,
    int* __restrict__ tile_ctr) {
  const int bid = blockIdx.x, tid = threadIdx.x;
  if (bid == 0 && tid == 0) *tile_ctr = 0;
  if (bid < 128) {
    int id = bid * 256 + tid;   // < 32768
    int lane = id & 63;
    int kt = (id >> 6) & 7;
    int mt = (id >> 9) & 3;
    int wv = (id >> 11) & 7;
    int dir = id >> 14;
    int rr = lane & 15;
    int n = wv * 64 + (rr >> 2) * 16 + mt * 4 + (rr & 3);
    int k0 = kt * 64 + (lane >> 4) * 16;
    const float* wp = (dir ? Whh_b : Whh_f) + (size_t)n * DLSTM + k0;
    signed char pkt[16];
#pragma unroll
    for (int q = 0; q < 4; ++q) {
      float4 v = *(const float4*)(wp + q * 4);
      float vv[4] = {v.x, v.y, v.z, v.w};
#pragma unroll
      for (int j = 0; j < 4; ++j) {
        int qq = (int)rintf(vv[j] * WSCALE);
        qq = qq > 127 ? 127 : (qq < -127 ? -127 : qq);
        pkt[q * 4 + j] = (signed char)qq;
      }
    }
    i32x4 v16;
    __builtin_memcpy(&v16, pkt, 16);
    *(i32x4*)&W8[(size_t)id * 16] = v16;
  } else {
    int id = (bid - 128) * 256 + tid;  // < 8192
    int lane = id & 63;
    int kt = (id >> 6) & 1;
    int mt = (id >> 7) & 3;
    int wv = (id >> 9) & 7;
    int dir = id >> 12;
    int rr = lane & 15;
    int n = wv * 64 + (rr >> 2) * 16 + mt * 4 + (rr & 3);
    int k0 = kt * 64 + (lane >> 4) * 16;
    const float* wp = (dir ? Wih_b : Wih_f) + (size_t)n * DSEQ + k0;
    signed char pkt[16];
#pragma unroll
    for (int q = 0; q < 4; ++q) {
      float4 v = *(const float4*)(wp + q * 4);
      float vv[4] = {v.x, v.y, v.z, v.w};
#pragma unroll
      for (int j = 0; j < 4; ++j) {
        int qq = (int)rintf(vv[j] * WSCALE);
        qq = qq > 127 ? 127 : (qq < -127 ? -127 : qq);
        pkt[q * 4 + j] = (signed char)qq;
      }
    }
    i32x4 v16;
    __builtin_memcpy(&v16, pkt, 16);
    *(i32x4*)&WX8[(size_t)id * 16] = v16;
  }
}

// ================= launch 2: fused scan (+input proj) + queued proj GEMM =================
// grid 256, block 512 (8 waves). Block bid: batch = bid>>1, dir = bid&1.
// Bounds computed in-block by binary search over sorted masks.
__global__ __launch_bounds__(512, 2) void fused_kernel(
    const float* __restrict__ seqs, const int* __restrict__ masks,
    const signed char* __restrict__ W8, const signed char* __restrict__ WX8,
    const float* __restrict__ b_f, const float* __restrict__ b_b,
    const float* __restrict__ x, const float* __restrict__ Wx,
    const float* __restrict__ bx, float* __restrict__ out,
    int* __restrict__ tile_ctr) {
  __shared__ __align__(16) char smem[21760];
  const int bid = blockIdx.x, tid = threadIdx.x;
  const int wv = tid >> 6, lane = tid & 63;

  // ---------------- scan phase ----------------
  {
    const int dir = bid & 1, bb = bid >> 1;
    const int chain = lane & 15, kgrp = lane >> 4;
    const int dbase = wv << 6;
    signed char* H = (signed char*)smem;             // [2][16][528]
    signed char* Xs = (signed char*)(smem + 16896);  // [2][16][144]
    int* meta = (int*)(smem + 21504);                // st[17] | ln[16] at +20

    // bounds via binary search (masks sorted ascending; every value present)
    if (tid < 17) {
      int target = bb * 16 + tid;
      int lo = 0, hi = T_N;
      while (lo < hi) {
        int mid = (lo + hi) >> 1;
        if (masks[mid] < target) lo = mid + 1; else hi = mid;
      }
      meta[tid] = lo;
    }
    {  // zero H[0]: 16 rows x 512B, 16B/thread
      int r = tid >> 5, o = (tid & 31) << 4;
      *(i32x4*)(H + r * 528 + o) = (i32x4){0, 0, 0, 0};
    }

    // register-resident weights: W_hh 32 frags (128 regs) + W_ih 8 frags (32 regs)
    i32x4 w[4][8], wx[4][2];
    {
      const signed char* wb = W8 + ((size_t)((dir << 3) + wv) << 15) + (lane << 4);
#pragma unroll
      for (int mt = 0; mt < 4; ++mt)
#pragma unroll
        for (int kt = 0; kt < 8; ++kt)
          w[mt][kt] = *(const i32x4*)(wb + (mt * 8 + kt) * 1024);
      const signed char* wxb = WX8 + ((size_t)((dir << 3) + wv) << 13) + (lane << 4);
#pragma unroll
      for (int mt = 0; mt < 4; ++mt)
#pragma unroll
        for (int kt = 0; kt < 2; ++kt)
          wx[mt][kt] = *(const i32x4*)(wxb + (mt * 2 + kt) * 1024);
    }
#pragma unroll
    for (int mt = 0; mt < 4; ++mt) {
#pragma unroll
      for (int kt = 0; kt < 8; ++kt) PIN(w[mt][kt]);
      PIN(wx[mt][0]); PIN(wx[mt][1]);
    }

    float bsc[16];
    {
      const float* bp = (dir ? b_b : b_f) + dbase + (kgrp << 4);
#pragma unroll
      for (int mt = 0; mt < 4; ++mt) {
        float4 u = *(const float4*)(bp + mt * 4);
        bsc[mt * 4 + 0] = u.x * LOG2E2; bsc[mt * 4 + 1] = u.y * LOG2E2;
        bsc[mt * 4 + 2] = u.z * LOG2E2; bsc[mt * 4 + 3] = u.w * LOG2E2;
      }
    }
    __syncthreads();
    if (tid < 16) meta[20 + tid] = meta[tid + 1] - meta[tid];
    __syncthreads();

    int maxlen = 0;
#pragma unroll
    for (int c = 0; c < 16; ++c) {
      int l = meta[20 + c];
      maxlen = maxlen > l ? maxlen : l;
    }
    const int myLen = meta[20 + chain];
    const int csn = (wv << 1) + (lane >> 5);           // chain this thread stages
    const int stStart = meta[csn], stLen = meta[20 + csn];
    const int jx = (lane & 31) << 2;                   // 4 floats of seq row

    // prologue: stage x(0)
    {
      int t0 = dir ? (stStart + stLen - 1) : stStart;
      float4 xv0 = *(const float4*)(seqs + (size_t)t0 * DSEQ + jx);
      unsigned c0 = __float_as_uint(fminf(fmaxf(xv0.x * SXQ, -127.f), 127.f) + MAGICF);
      unsigned c1 = __float_as_uint(fminf(fmaxf(xv0.y * SXQ, -127.f), 127.f) + MAGICF);
      unsigned c2 = __float_as_uint(fminf(fmaxf(xv0.z * SXQ, -127.f), 127.f) + MAGICF);
      unsigned c3 = __float_as_uint(fminf(fmaxf(xv0.w * SXQ, -127.f), 127.f) + MAGICF);
      *(unsigned*)(Xs + csn * 144 + jx) =
          (c0 & 255u) | ((c1 & 255u) << 8) | ((c2 & 255u) << 16) | ((c3 & 255u) << 24);
    }
    __syncthreads();

    float pool[4][4];
#pragma unroll
    for (int mt = 0; mt < 4; ++mt)
#pragma unroll
      for (int r = 0; r < 4; ++r) pool[mt][r] = 0.f;

    int cur = 0;
    for (int s = 0; s < maxlen; ++s) {
      // issue next-step x load early (consumed at bottom of this body)
      int sn = (s + 1 < stLen) ? (s + 1) : (stLen - 1);
      int tn = dir ? (stStart + stLen - 1 - sn) : (stStart + sn);
      float4 xv = *(const float4*)(seqs + (size_t)tn * DSEQ + jx);

      i32x4 acc[4], ax[4];
#pragma unroll
      for (int mt = 0; mt < 4; ++mt) {
        acc[mt] = (i32x4){0, 0, 0, 0};
        ax[mt] = (i32x4){0, 0, 0, 0};
      }
      {
        const signed char* xr = Xs + cur * 2304 + chain * 144;
#pragma unroll
        for (int kt = 0; kt < 2; ++kt) {
          i32x4 xb = *(const i32x4*)(xr + kt * 64 + (kgrp << 4));
#pragma unroll
          for (int mt = 0; mt < 4; ++mt)
            ax[mt] = __builtin_amdgcn_mfma_i32_16x16x64_i8(wx[mt][kt], xb, ax[mt], 0, 0, 0);
        }
        const signed char* hr = H + cur * 8448 + chain * 528;
        __builtin_amdgcn_s_setprio(1);
#pragma unroll
        for (int kt = 0; kt < 8; ++kt) {
          i32x4 hb = *(const i32x4*)(hr + kt * 64 + (kgrp << 4));
#pragma unroll
          for (int mt = 0; mt < 4; ++mt)
            acc[mt] = __builtin_amdgcn_mfma_i32_16x16x64_i8(w[mt][kt], hb, acc[mt], 0, 0, 0);
        }
        __builtin_amdgcn_s_setprio(0);
      }

      const float msk = (s < myLen) ? 1.f : 0.f;
      unsigned hw[4];
      float rcs[4][4];
#pragma unroll
      for (int mt = 0; mt < 4; ++mt) {
        unsigned b[4];
#pragma unroll
        for (int r = 0; r < 4; ++r) {
          int comb = acc[mt][r] + (ax[mt][r] << 3);     // DEQX = 8*DEQH
          float x2 = fmaf((float)comb, DEQH, bsc[mt * 4 + r]);
          float e = EXP2F(x2);
          float rc = RCPF(e + 1.f);
          rcs[mt][r] = rc;
          b[r] = __float_as_uint(fmaf(-254.f, rc, MAGIC_C));
        }
        hw[mt] = (b[0] & 255u) | ((b[1] & 255u) << 8) | ((b[2] & 255u) << 16) | (b[3] << 24);
      }
      // issue the H write ASAP; pool updates (no LDS dependency) fill the drain window
      *(uint4*)(H + (cur ^ 1) * 8448 + chain * 528 + dbase + (kgrp << 4)) =
          make_uint4(hw[0], hw[1], hw[2], hw[3]);
      {
        unsigned c0 = __float_as_uint(fminf(fmaxf(xv.x * SXQ, -127.f), 127.f) + MAGICF);
        unsigned c1 = __float_as_uint(fminf(fmaxf(xv.y * SXQ, -127.f), 127.f) + MAGICF);
        unsigned c2 = __float_as_uint(fminf(fmaxf(xv.z * SXQ, -127.f), 127.f) + MAGICF);
        unsigned c3 = __float_as_uint(fminf(fmaxf(xv.w * SXQ, -127.f), 127.f) + MAGICF);
        *(unsigned*)(Xs + (cur ^ 1) * 2304 + csn * 144 + jx) =
            (c0 & 255u) | ((c1 & 255u) << 8) | ((c2 & 255u) << 16) | ((c3 & 255u) << 24);
      }
#pragma unroll
      for (int mt = 0; mt < 4; ++mt)
#pragma unroll
        for (int r = 0; r < 4; ++r)
          pool[mt][r] = fmaf(rcs[mt][r], msk, pool[mt][r]);

      asm volatile("s_waitcnt lgkmcnt(0)" ::: "memory");
      __builtin_amdgcn_s_barrier();
      __builtin_amdgcn_sched_barrier(0);
      cur ^= 1;
    }

    const int sid = bb * 16 + chain;
    const float s2 = -2.0f / (float)myLen;
    float* op = out + (size_t)sid * OUTW + DPROJ + dir * DLSTM + dbase + (kgrp << 4);
#pragma unroll
    for (int mt = 0; mt < 4; ++mt)
      *(float4*)(op + mt * 4) =
          make_float4(fmaf(s2, pool[mt][0], 1.f), fmaf(s2, pool[mt][1], 1.f),
                      fmaf(s2, pool[mt][2], 1.f), fmaf(s2, pool[mt][3], 1.f));
  }

  // ---------------- queued proj GEMM: blocks pull 128x128 tiles as they free up ----------------
  {
    int* tileslot = (int*)(smem + 21696);
    unsigned short (*As)[40] = (unsigned short(*)[40])smem;               // [128][40]
    unsigned short (*Bs)[40] = (unsigned short(*)[40])(smem + 10240);     // [128][40]
    const int rowA = lane & 15, kgrp = lane >> 4;
    const int wm = (wv & 1) << 6, wn = (wv >> 1) << 5;
    const int srow = tid >> 2, skc = (tid & 3) << 3;

    for (;;) {
      __syncthreads();   // smem quiescent (scan done / previous tile done)
      if (tid == 0) *tileslot = atomicAdd(tile_ctr, 1);
      __syncthreads();
      const int tile = *tileslot;
      if (tile >= 128) break;
      const int m0 = (tile >> 3) << 7, n0 = (tile & 7) << 7;

      f32x4 acc[4][2];
#pragma unroll
      for (int i = 0; i < 4; ++i)
#pragma unroll
        for (int j = 0; j < 2; ++j) acc[i][j] = (f32x4){0.f, 0.f, 0.f, 0.f};

      for (int k0 = 0; k0 < DX; k0 += 32) {
        __syncthreads();
        {
          const float* ap = x + (size_t)(m0 + srow) * DX + k0 + skc;
          float4 va0 = *(const float4*)ap;
          float4 va1 = *(const float4*)(ap + 4);
          unsigned wa[4] = {cvtpk(va0.x, va0.y), cvtpk(va0.z, va0.w),
                            cvtpk(va1.x, va1.y), cvtpk(va1.z, va1.w)};
          *(uint4*)&As[srow][skc] = *(uint4*)wa;
          const float* bp = Wx + (size_t)(n0 + srow) * DX + k0 + skc;
          float4 vb0 = *(const float4*)bp;
          float4 vb1 = *(const float4*)(bp + 4);
          unsigned wb2[4] = {cvtpk(vb0.x, vb0.y), cvtpk(vb0.z, vb0.w),
                             cvtpk(vb1.x, vb1.y), cvtpk(vb1.z, vb1.w)};
          *(uint4*)&Bs[srow][skc] = *(uint4*)wb2;
        }
        __syncthreads();
        short8 af[4], bf[2];
#pragma unroll
        for (int mt = 0; mt < 4; ++mt)
          af[mt] = *(const short8*)&As[wm + mt * 16 + rowA][kgrp << 3];
#pragma unroll
        for (int nt = 0; nt < 2; ++nt)
          bf[nt] = *(const short8*)&Bs[wn + nt * 16 + rowA][kgrp << 3];
#pragma unroll
        for (int mt = 0; mt < 4; ++mt)
#pragma unroll
          for (int nt = 0; nt < 2; ++nt)
            acc[mt][nt] = __builtin_amdgcn_mfma_f32_16x16x32_bf16(af[mt], bf[nt], acc[mt][nt], 0, 0, 0);
      }

#pragma unroll
      for (int mt = 0; mt < 4; ++mt)
#pragma unroll
        for (int nt = 0; nt < 2; ++nt) {
          int n = n0 + wn + nt * 16 + rowA;
          float bv = bx[n];
#pragma unroll
          for (int r = 0; r < 4; ++r) {
            int m = m0 + wm + mt * 16 + (kgrp << 2) + r;
            out[(size_t)m * OUTW + n] = acc[mt][nt][r] + bv;
          }
        }
    }
  }
}

extern "C" void kernel_launch(void* const* d_in, const int* in_sizes, int n_in,
                              void* d_out, int out_size, void* d_ws, size_t ws_size,
                              hipStream_t stream) {
  const float* x     = (const float*)d_in[0];
  const float* seqs  = (const float*)d_in[1];
  const int*   masks = (const int*)d_in[2];
  const float* Wih_f = (const float*)d_in[3];
  const float* Whh_f = (const float*)d_in[4];
  const float* b_f   = (const float*)d_in[5];
  const float* Wih_b = (const float*)d_in[6];
  const float* Whh_b = (const float*)d_in[7];
  const float* b_b   = (const float*)d_in[8];
  const float* Wx    = (const float*)d_in[9];
  const float* bx    = (const float*)d_in[10];
  float* out = (float*)d_out;

  char* ws = (char*)d_ws;
  signed char* W8  = (signed char*)ws;                        // 512 KB
  signed char* WX8 = (signed char*)(ws + (size_t)512 * 1024); // 128 KB
  int* tile_ctr = (int*)(ws + (size_t)640 * 1024);

  prep_kernel<<<160, 256, 0, stream>>>(Whh_f, Whh_b, Wih_f, Wih_b, W8, WX8, tile_ctr);
  fused_kernel<<<256, 512, 0, stream>>>(seqs, masks, W8, WX8,
                                        b_f, b_b, x, Wx, bx, out, tile_ctr);
}